// Round 2
// baseline (164.689 us; speedup 1.0000x reference)
//
#include <hip/hip_runtime.h>
#include <hip/hip_bf16.h>

// ---------------------------------------------------------------------------
// OuterProductMean (AlphaFold) fused MFMA implementation for gfx950.
//   B=1, N=128 (MSA depth), L=256, C_M=256, C_H=32, C_Z=128
// Pipeline (3 launches):
//   k_prep    : [Wa|Wb] fp32 -> WT bf16 [64][256] (h-major, c contiguous)
//   k_ln_proj : main blocks: LayerNorm + a/b projection (MFMA) -> aT/bT bf16
//               [8192][128] (row = l*32+h, col = MSA index n -> K-contiguous).
//               tail: W2 = Wo bf16 fragment-sequential; pm_recip.
//   k_outer   : v3 — v2 (8i x 4j, grid 2048, global_load_lds staging) plus a
//               depth-4 register ring for the stage-2 W2 fragments.
//               Rationale (R2): VGPR_Count=64 showed prefetch depth 1; each
//               stage-2 iter stalled ~250cy on a dependent L2 load against
//               ~10cy of MFMA issue -> stage 2 alone ~26us of the 58us.
//               Ring is preloaded BEFORE stage 1 (completes under staging),
//               loop fully unrolled so ring indices are compile-time (no
//               scratch). Predicted: k_outer 58 -> ~35us, MfmaUtil ~24->38%.
// ---------------------------------------------------------------------------

typedef __attribute__((ext_vector_type(8))) short bf8_t;   // 8 x bf16 (4 VGPRs)
typedef __attribute__((ext_vector_type(4))) float f32x4;   // MFMA accumulator

__device__ __forceinline__ unsigned short f2bf(float f) {
    unsigned int u = __float_as_uint(f);
    u += 0x7fffu + ((u >> 16) & 1u);        // RNE (finite values only)
    return (unsigned short)(u >> 16);
}
__device__ __forceinline__ unsigned int pack2(float a, float b) {
    return (unsigned int)f2bf(a) | ((unsigned int)f2bf(b) << 16);
}

// async 16B global -> LDS (dest = wave-uniform base + lane*16, linear)
__device__ __forceinline__ void cp16_async(const void* g, void* l) {
    __builtin_amdgcn_global_load_lds(
        (const __attribute__((address_space(1))) unsigned int*)g,
        (__attribute__((address_space(3))) unsigned int*)l, 16, 0, 0);
}

// ---------------------------------------------------------------------------
// WT[h][c] = (h<32 ? Wa[c][h] : Wb[c][h-32]), bf16. 16384 elems, 64 blocks.
__global__ __launch_bounds__(256) void k_prep(const float* __restrict__ Wa,
                                              const float* __restrict__ Wb,
                                              unsigned short* __restrict__ WTb) {
    int u = blockIdx.x * 256 + threadIdx.x;          // u = h*256 + c
    int h = u >> 8, c = u & 255;
    float v = (h < 32) ? Wa[c * 32 + h] : Wb[c * 32 + (h - 32)];
    WTb[u] = f2bf(v);
}

// ---------------------------------------------------------------------------
// Blocks [0,2048): LayerNorm + projection. Blocks [2048,2560): W2 build.
// Blocks [2560,2816): pair-mask reciprocal.
__global__ __launch_bounds__(256) void k_ln_proj(
    const float* __restrict__ gm, const float* __restrict__ gmask,
    const float* __restrict__ gamma, const float* __restrict__ beta,
    const unsigned short* __restrict__ WTb,
    const float* __restrict__ ba, const float* __restrict__ bb,
    const float* __restrict__ Wo,
    unsigned short* __restrict__ aT, unsigned short* __restrict__ bT,
    unsigned short* __restrict__ W2, float* __restrict__ pmr)
{
    const int tid = threadIdx.x;
    const int tail = (int)blockIdx.x - 2048;
    if (tail >= 0) {
        if (tail < 512) {
            // W2 fragment-sequential: (zg=z>>4, s=k'>>5, r16=z&15, kg=(k'>>3)&3, e=k'&7)
            // with k' = d*32+c, Wo element index u = (c*32+d)*128 + z.
            int u = tail * 256 + tid;                // u = k*128 + z (coalesced read)
            int k = u >> 7, z = u & 127;
            int c = k >> 5, d = k & 31;
            int kp = d * 32 + c;
            int dst = (((z >> 4) * 32 + (kp >> 5)) * 16 + (z & 15)) * 32
                      + ((kp >> 3) & 3) * 8 + (kp & 7);
            W2[dst] = f2bf(Wo[u]);
        } else {
            int u = (tail - 512) * 256 + tid;        // u = i*256 + j
            int i = u >> 8, j = u & 255;
            float s = 0.f;
            #pragma unroll 8
            for (int n = 0; n < 128; n++)
                s += gmask[n * 256 + i] * gmask[n * 256 + j];
            pmr[u] = 1.f / (s + 1e-8f);
        }
        return;
    }

    __shared__ __align__(16) unsigned short xlb[16 * 256]; // [row][c] bf16, swizzled
    __shared__ float vl[16 * 64];                          // [n-row][h]
    const int lane = tid & 63, w = tid >> 6;
    const int l = blockIdx.x & 255, n0 = ((int)blockIdx.x >> 8) << 4;

    const float4 g4  = ((const float4*)gamma)[lane];
    const float4 be4 = ((const float4*)beta)[lane];

    // ---- phase 1: LN (wave per row, 4 rows per wave) ----
    #pragma unroll
    for (int j = 0; j < 4; j++) {
        int row = w * 4 + j;
        int n = n0 + row;
        float4 v = ((const float4*)(gm + ((size_t)n * 256 + l) * 256))[lane];
        float s = v.x + v.y + v.z + v.w;
        float q = v.x * v.x + v.y * v.y + v.z * v.z + v.w * v.w;
        #pragma unroll
        for (int off = 1; off < 64; off <<= 1) {
            s += __shfl_xor(s, off);
            q += __shfl_xor(q, off);
        }
        float mean = s * (1.f / 256.f);
        float var = fmaxf(q * (1.f / 256.f) - mean * mean, 0.f);
        float rstd = rsqrtf(var + 1e-5f);
        float x0 = (v.x - mean) * rstd * g4.x + be4.x;
        float x1 = (v.y - mean) * rstd * g4.y + be4.y;
        float x2 = (v.z - mean) * rstd * g4.z + be4.z;
        float x3 = (v.w - mean) * rstd * g4.w + be4.w;
        int c8s = lane ^ ((row & 7) << 1);               // 8B-chunk XOR swizzle
        *(uint2*)((char*)xlb + row * 512 + (c8s << 3)) =
            make_uint2(pack2(x0, x1), pack2(x2, x3));
    }
    __syncthreads();

    // ---- phase 2: projection via MFMA (wave w -> h-cols w*16..w*16+15) ----
    const int kg = lane >> 4, r16 = lane & 15;
    const int h = w * 16 + r16;
    f32x4 acc = {0.f, 0.f, 0.f, 0.f};
    #pragma unroll
    for (int ks = 0; ks < 8; ks++) {
        int c8 = ks * 8 + kg * 2;                        // even -> 16B pair intact
        bf8_t af = *(const bf8_t*)((char*)xlb + r16 * 512 +
                                   ((c8 ^ ((r16 & 7) << 1)) << 3));
        bf8_t wf = *(const bf8_t*)(WTb + (size_t)h * 256 + ks * 32 + kg * 8);
        acc = __builtin_amdgcn_mfma_f32_16x16x32_bf16(af, wf, acc, 0, 0, 0);
    }
    float bias = (h < 32) ? ba[h] : bb[h - 32];
    #pragma unroll
    for (int r = 0; r < 4; r++) {
        int nrow = kg * 4 + r;                           // C/D row = MSA row index
        float mk = gmask[(size_t)(n0 + nrow) * 256 + l];
        vl[nrow * 64 + h] = (acc[r] + bias) * mk;
    }
    __syncthreads();

    // ---- phase 3: repack, 8 n-values per thread, 16B stores ----
    if (tid < 128) {
        int row = tid >> 1, half = tid & 1;              // row = h index 0..63
        int hh = row & 31;
        unsigned short* dst = (row < 32) ? aT : bT;
        unsigned int pk[4];
        #pragma unroll
        for (int jj = 0; jj < 4; jj++)
            pk[jj] = pack2(vl[(half * 8 + 2 * jj) * 64 + row],
                           vl[(half * 8 + 2 * jj + 1) * 64 + row]);
        *(uint4*)(dst + ((size_t)l * 32 + hh) * 128 + n0 + half * 8) =
            make_uint4(pk[0], pk[1], pk[2], pk[3]);
    }
}

// ---------------------------------------------------------------------------
// Fused outer-product + Wo projection, v3.
// Grid 2048 = 64 tj (fast) x 32 ti. 512 thr = 8 waves; 64KB LDS.
// Stage 1: 256(i.h) x 128(j.h) outer tile, K=128 in two halves of 64.
//   Wave grid 4(wr) x 2(wc) -> per-wave 64x64 -> acc[4][4].
//   Staging: global_load_lds w=16, source pre-swizzled (LDS linear).
// Stage 2: Z[32 pairs,128] = O2[32,1024] @ W2[1024,128]; wave w -> z-tile w
//   (16 z), m-tiles {0,1}; W2 slice read ONCE per block; depth-4 register
//   ring on W2 fragments (preloaded before stage 1, fully unrolled loop).
__global__ __launch_bounds__(512, 4) void k_outer(
    const unsigned short* __restrict__ aT, const unsigned short* __restrict__ bT,
    const unsigned short* __restrict__ W2, const float* __restrict__ pmr,
    const float* __restrict__ bo, float* __restrict__ out)
{
    __shared__ __align__(16) char smem[65536];
    const int tid = threadIdx.x, lane = tid & 63, w = tid >> 6;   // 8 waves
    const int wr = w >> 1, wc = w & 1;
    const int tj = blockIdx.x & 63, ti = blockIdx.x >> 6;         // ti 0..31
    const int kg = lane >> 4, r16 = lane & 15;

    f32x4 acc[4][4];
    #pragma unroll
    for (int mt = 0; mt < 4; mt++)
        #pragma unroll
        for (int nt = 0; nt < 4; nt++)
            acc[mt][nt] = (f32x4){0.f, 0.f, 0.f, 0.f};

    const uint4* gA = (const uint4*)(aT + (size_t)ti * 32768);    // 8i x 32h x 128n
    const uint4* gB = (const uint4*)(bT + (size_t)tj * 16384);    // 4j x 32h x 128n

    // ---- W2 ring preload (completes for free under stage-1 staging) ----
    const unsigned short* wz = W2 + (size_t)w * 16384 + r16 * 32 + kg * 8;
    bf8_t wbuf[4];
    #pragma unroll
    for (int s = 0; s < 4; s++)
        wbuf[s] = *(const bf8_t*)(wz + s * 512);

    // ---- stage 1: two K=64 halves; A 32KB @0, B 16KB @32768 ----
    #pragma unroll
    for (int half = 0; half < 2; half++) {
        // async stage: LDS[row][c] = global chunk (c ^ (row&7))  (read undoes XOR)
        #pragma unroll
        for (int t = 0; t < 4; t++) {                    // A: 2048 chunks / 8w / 64l
            int q = w * 256 + t * 64 + lane;
            int row = q >> 3, c = q & 7;
            cp16_async(gA + row * 16 + half * 8 + (c ^ (row & 7)),
                       smem + ((w * 256 + t * 64) << 4));
        }
        #pragma unroll
        for (int t = 0; t < 2; t++) {                    // B: 1024 chunks
            int q = w * 128 + t * 64 + lane;
            int row = q >> 3, c = q & 7;
            cp16_async(gB + row * 16 + half * 8 + (c ^ (row & 7)),
                       smem + 32768 + ((w * 128 + t * 64) << 4));
        }
        __syncthreads();                                  // vmcnt(0) drained here

        #pragma unroll
        for (int ks2 = 0; ks2 < 2; ks2++) {
            int ch = ks2 * 4 + kg;
            bf8_t af[4];
            #pragma unroll
            for (int mt = 0; mt < 4; mt++) {
                int mm = wr * 64 + mt * 16 + r16;
                af[mt] = *(const bf8_t*)(smem + mm * 128 + ((ch ^ (mm & 7)) << 4));
            }
            #pragma unroll
            for (int nt = 0; nt < 4; nt++) {
                int nn = wc * 64 + nt * 16 + r16;
                bf8_t bfr = *(const bf8_t*)(smem + 32768 + nn * 128 +
                                            ((ch ^ (nn & 7)) << 4));
                #pragma unroll
                for (int mt = 0; mt < 4; mt++)
                    acc[mt][nt] = __builtin_amdgcn_mfma_f32_16x16x32_bf16(
                        af[mt], bfr, acc[mt][nt], 0, 0, 0);
            }
        }
        __syncthreads();   // LDS free for next half / the transpose
    }

    // ---- transpose accs -> O2b[p][k2] bf16 in LDS, A-fragment order ----
    // p = i_loc*4 + j_loc (32 pairs); k2 = (nn&31)*32 + (mm&31);
    // chunk c2=k2>>3; pc = c2 ^ ((c2>>3)&7) ^ (p&7) spreads banks.
    unsigned short* O2b = (unsigned short*)smem;        // 32 x 1024 bf16 = 64 KB
    #pragma unroll
    for (int mt = 0; mt < 4; mt++) {
        int mmb = wr * 64 + mt * 16 + kg * 4;           // + r (r stays in-chunk)
        #pragma unroll
        for (int nt = 0; nt < 4; nt++) {
            int nn = wc * 64 + nt * 16 + r16;
            int p  = ((mmb >> 5) << 2) | (nn >> 5);     // pair = i_loc*4 + j_loc
            int k2 = ((nn & 31) << 5) | (mmb & 31);
            int c2 = k2 >> 3;
            int pc = c2 ^ ((c2 >> 3) & 7) ^ (p & 7);
            *(uint2*)(O2b + p * 1024 + pc * 8 + (k2 & 7)) =
                make_uint2(pack2(acc[mt][nt][0], acc[mt][nt][1]),
                           pack2(acc[mt][nt][2], acc[mt][nt][3]));
        }
    }
    __syncthreads();

    // ---- stage 2: Z[32 pairs, 128] = O2[32,1024] @ Wo[1024,128] ----
    // Wave w -> z in [w*16, w*16+16): 32KB W2 slice read once, shared by the
    // 2 m-tiles. Depth-4 ring keeps 4 W2 loads in flight (x3 waves/SIMD ->
    // iteration rate becomes MFMA-issue-bound instead of L2-latency-bound).
    f32x4 acc2[2];
    acc2[0] = (f32x4){0.f, 0.f, 0.f, 0.f};
    acc2[1] = (f32x4){0.f, 0.f, 0.f, 0.f};
    const unsigned short* O2r = O2b + r16 * 1024;        // A-row = pair (m-tile 0)
    const int psw = r16 & 7;                             // p&7 same for both m-tiles
    #pragma unroll
    for (int s = 0; s < 32; s++) {
        bf8_t wf = wbuf[s & 3];                          // static idx (full unroll)
        if (s + 4 < 32)
            wbuf[s & 3] = *(const bf8_t*)(wz + (s + 4) * 512);
        int c2 = s * 4 + kg;
        int pc = c2 ^ ((c2 >> 3) & 7) ^ psw;
        bf8_t a0 = *(const bf8_t*)(O2r + pc * 8);
        bf8_t a1 = *(const bf8_t*)(O2r + 16384 + pc * 8);   // m-tile 1 (+16 rows)
        acc2[0] = __builtin_amdgcn_mfma_f32_16x16x32_bf16(a0, wf, acc2[0], 0, 0, 0);
        acc2[1] = __builtin_amdgcn_mfma_f32_16x16x32_bf16(a1, wf, acc2[1], 0, 0, 0);
    }

    // ---- epilogue: scale by 1/(pair_mask+eps), add bias, store ----
    const int i0 = ti * 8, j0 = tj * 4;
    const int z = w * 16 + r16;
    const float boz = bo[z];
    #pragma unroll
    for (int mt = 0; mt < 2; mt++)
        #pragma unroll
        for (int r = 0; r < 4; r++) {
            int p = mt * 16 + kg * 4 + r;
            int i = i0 + (p >> 2), j = j0 + (p & 3);
            float recip = pmr[i * 256 + j];
            out[((size_t)(i * 256 + j)) * 128 + z] = acc2[mt][r] * recip + boz;
        }
}

// ---------------------------------------------------------------------------
extern "C" void kernel_launch(void* const* d_in, const int* in_sizes, int n_in,
                              void* d_out, int out_size, void* d_ws, size_t ws_size,
                              hipStream_t stream)
{
    const float* m    = (const float*)d_in[0];
    const float* mask = (const float*)d_in[1];
    const float* gam  = (const float*)d_in[2];
    const float* bet  = (const float*)d_in[3];
    const float* Wa   = (const float*)d_in[4];
    const float* ba   = (const float*)d_in[5];
    const float* Wb   = (const float*)d_in[6];
    const float* bb   = (const float*)d_in[7];
    const float* Wo   = (const float*)d_in[8];
    const float* bo   = (const float*)d_in[9];
    float* out = (float*)d_out;

    unsigned short* aT  = (unsigned short*)d_ws;           // 8192*128 bf16 = 2 MB
    unsigned short* bT  = aT + 8192 * 128;                 // 2 MB
    unsigned short* W2  = bT + 8192 * 128;                 // 128*1024 bf16 = 256 KB
    unsigned short* WTb = W2 + 128 * 1024;                 // 64*256 bf16 = 32 KB
    float* pmr = (float*)(WTb + 64 * 256);                 // 256*256 fp32 = 256 KB

    k_prep   <<<  64, 256, 0, stream>>>(Wa, Wb, WTb);
    k_ln_proj<<<2816, 256, 0, stream>>>(m, mask, gam, bet, WTb, ba, bb, Wo,
                                        aT, bT, W2, pmr);
    k_outer  <<<2048, 512, 0, stream>>>(aT, bT, W2, pmr, bo, out);
}

// Round 4
// 157.474 us; speedup vs baseline: 1.0458x; 1.0458x over previous
//
#include <hip/hip_runtime.h>
#include <hip/hip_bf16.h>

// ---------------------------------------------------------------------------
// OuterProductMean (AlphaFold) fused MFMA implementation for gfx950.
//   B=1, N=128 (MSA depth), L=256, C_M=256, C_H=32, C_Z=128
// Pipeline (3 launches):
//   k_prep    : [Wa|Wb] fp32 -> WT bf16 [64][256] (h-major, c contiguous)
//   k_ln_proj : main blocks: LayerNorm + a/b projection (MFMA) -> aT/bT bf16
//               [8192][128] (row = l*32+h, col = MSA index n -> K-contiguous).
//               tail: W2 = Wo bf16 fragment-sequential; pm_recip.
//   k_outer   : v5 — v4 (8i x 4j, grid 2048, global_load_lds staging, depth-8
//               stage-2 W2 register ring after the transpose barrier) with
//               the v4 ring ORDERING BUG fixed: v4's macro prefetched into
//               wN BEFORE the MFMA consumed wN (used future fragment ->
//               absmax 0.11). v5 snapshots wcur = wN first, then issues the
//               prefetch, then feeds wcur to the MFMAs (register renaming
//               keeps the load early; semantics now match v2/v3).
//               History: v3 preloaded the ring BEFORE stage 1 -> ring regs
//               live across the acc[4][4] pressure peak -> scratch spill
//               (WRITE_SIZE 32.8->62.3 MB). Ring lives only in stage 2 here.
// ---------------------------------------------------------------------------

typedef __attribute__((ext_vector_type(8))) short bf8_t;   // 8 x bf16 (4 VGPRs)
typedef __attribute__((ext_vector_type(4))) float f32x4;   // MFMA accumulator

__device__ __forceinline__ unsigned short f2bf(float f) {
    unsigned int u = __float_as_uint(f);
    u += 0x7fffu + ((u >> 16) & 1u);        // RNE (finite values only)
    return (unsigned short)(u >> 16);
}
__device__ __forceinline__ unsigned int pack2(float a, float b) {
    return (unsigned int)f2bf(a) | ((unsigned int)f2bf(b) << 16);
}

// async 16B global -> LDS (dest = wave-uniform base + lane*16, linear)
__device__ __forceinline__ void cp16_async(const void* g, void* l) {
    __builtin_amdgcn_global_load_lds(
        (const __attribute__((address_space(1))) unsigned int*)g,
        (__attribute__((address_space(3))) unsigned int*)l, 16, 0, 0);
}

// ---------------------------------------------------------------------------
// WT[h][c] = (h<32 ? Wa[c][h] : Wb[c][h-32]), bf16. 16384 elems, 64 blocks.
__global__ __launch_bounds__(256) void k_prep(const float* __restrict__ Wa,
                                              const float* __restrict__ Wb,
                                              unsigned short* __restrict__ WTb) {
    int u = blockIdx.x * 256 + threadIdx.x;          // u = h*256 + c
    int h = u >> 8, c = u & 255;
    float v = (h < 32) ? Wa[c * 32 + h] : Wb[c * 32 + (h - 32)];
    WTb[u] = f2bf(v);
}

// ---------------------------------------------------------------------------
// Blocks [0,2048): LayerNorm + projection. Blocks [2048,2560): W2 build.
// Blocks [2560,2816): pair-mask reciprocal.
__global__ __launch_bounds__(256) void k_ln_proj(
    const float* __restrict__ gm, const float* __restrict__ gmask,
    const float* __restrict__ gamma, const float* __restrict__ beta,
    const unsigned short* __restrict__ WTb,
    const float* __restrict__ ba, const float* __restrict__ bb,
    const float* __restrict__ Wo,
    unsigned short* __restrict__ aT, unsigned short* __restrict__ bT,
    unsigned short* __restrict__ W2, float* __restrict__ pmr)
{
    const int tid = threadIdx.x;
    const int tail = (int)blockIdx.x - 2048;
    if (tail >= 0) {
        if (tail < 512) {
            // W2 fragment-sequential: (zg=z>>4, s=k'>>5, r16=z&15, kg=(k'>>3)&3, e=k'&7)
            // with k' = d*32+c, Wo element index u = (c*32+d)*128 + z.
            int u = tail * 256 + tid;                // u = k*128 + z (coalesced read)
            int k = u >> 7, z = u & 127;
            int c = k >> 5, d = k & 31;
            int kp = d * 32 + c;
            int dst = (((z >> 4) * 32 + (kp >> 5)) * 16 + (z & 15)) * 32
                      + ((kp >> 3) & 3) * 8 + (kp & 7);
            W2[dst] = f2bf(Wo[u]);
        } else {
            int u = (tail - 512) * 256 + tid;        // u = i*256 + j
            int i = u >> 8, j = u & 255;
            float s = 0.f;
            #pragma unroll 8
            for (int n = 0; n < 128; n++)
                s += gmask[n * 256 + i] * gmask[n * 256 + j];
            pmr[u] = 1.f / (s + 1e-8f);
        }
        return;
    }

    __shared__ __align__(16) unsigned short xlb[16 * 256]; // [row][c] bf16, swizzled
    __shared__ float vl[16 * 64];                          // [n-row][h]
    const int lane = tid & 63, w = tid >> 6;
    const int l = blockIdx.x & 255, n0 = ((int)blockIdx.x >> 8) << 4;

    const float4 g4  = ((const float4*)gamma)[lane];
    const float4 be4 = ((const float4*)beta)[lane];

    // ---- phase 1: LN (wave per row, 4 rows per wave) ----
    #pragma unroll
    for (int j = 0; j < 4; j++) {
        int row = w * 4 + j;
        int n = n0 + row;
        float4 v = ((const float4*)(gm + ((size_t)n * 256 + l) * 256))[lane];
        float s = v.x + v.y + v.z + v.w;
        float q = v.x * v.x + v.y * v.y + v.z * v.z + v.w * v.w;
        #pragma unroll
        for (int off = 1; off < 64; off <<= 1) {
            s += __shfl_xor(s, off);
            q += __shfl_xor(q, off);
        }
        float mean = s * (1.f / 256.f);
        float var = fmaxf(q * (1.f / 256.f) - mean * mean, 0.f);
        float rstd = rsqrtf(var + 1e-5f);
        float x0 = (v.x - mean) * rstd * g4.x + be4.x;
        float x1 = (v.y - mean) * rstd * g4.y + be4.y;
        float x2 = (v.z - mean) * rstd * g4.z + be4.z;
        float x3 = (v.w - mean) * rstd * g4.w + be4.w;
        int c8s = lane ^ ((row & 7) << 1);               // 8B-chunk XOR swizzle
        *(uint2*)((char*)xlb + row * 512 + (c8s << 3)) =
            make_uint2(pack2(x0, x1), pack2(x2, x3));
    }
    __syncthreads();

    // ---- phase 2: projection via MFMA (wave w -> h-cols w*16..w*16+15) ----
    const int kg = lane >> 4, r16 = lane & 15;
    const int h = w * 16 + r16;
    f32x4 acc = {0.f, 0.f, 0.f, 0.f};
    #pragma unroll
    for (int ks = 0; ks < 8; ks++) {
        int c8 = ks * 8 + kg * 2;                        // even -> 16B pair intact
        bf8_t af = *(const bf8_t*)((char*)xlb + r16 * 512 +
                                   ((c8 ^ ((r16 & 7) << 1)) << 3));
        bf8_t wf = *(const bf8_t*)(WTb + (size_t)h * 256 + ks * 32 + kg * 8);
        acc = __builtin_amdgcn_mfma_f32_16x16x32_bf16(af, wf, acc, 0, 0, 0);
    }
    float bias = (h < 32) ? ba[h] : bb[h - 32];
    #pragma unroll
    for (int r = 0; r < 4; r++) {
        int nrow = kg * 4 + r;                           // C/D row = MSA row index
        float mk = gmask[(size_t)(n0 + nrow) * 256 + l];
        vl[nrow * 64 + h] = (acc[r] + bias) * mk;
    }
    __syncthreads();

    // ---- phase 3: repack, 8 n-values per thread, 16B stores ----
    if (tid < 128) {
        int row = tid >> 1, half = tid & 1;              // row = h index 0..63
        int hh = row & 31;
        unsigned short* dst = (row < 32) ? aT : bT;
        unsigned int pk[4];
        #pragma unroll
        for (int jj = 0; jj < 4; jj++)
            pk[jj] = pack2(vl[(half * 8 + 2 * jj) * 64 + row],
                           vl[(half * 8 + 2 * jj + 1) * 64 + row]);
        *(uint4*)(dst + ((size_t)l * 32 + hh) * 128 + n0 + half * 8) =
            make_uint4(pk[0], pk[1], pk[2], pk[3]);
    }
}

// ---------------------------------------------------------------------------
// Fused outer-product + Wo projection, v5.
// Grid 2048 = 64 tj (fast) x 32 ti. 512 thr = 8 waves; 64KB LDS.
// Stage 1: 256(i.h) x 128(j.h) outer tile, K=128 in two halves of 64.
//   Wave grid 4(wr) x 2(wc) -> per-wave 64x64 -> acc[4][4].
//   Staging: global_load_lds w=16, source pre-swizzled (LDS linear).
// Stage 2: Z[32 pairs,128] = O2[32,1024] @ W2[1024,128]; wave w -> z-tile w
//   (16 z), m-tiles {0,1}; W2 slice read ONCE per block; depth-8 named
//   register ring (initiated after transpose barrier, fully unrolled,
//   snapshot-before-prefetch so the MFMA reads the CURRENT fragment).
__global__ __launch_bounds__(512, 3) void k_outer(
    const unsigned short* __restrict__ aT, const unsigned short* __restrict__ bT,
    const unsigned short* __restrict__ W2, const float* __restrict__ pmr,
    const float* __restrict__ bo, float* __restrict__ out)
{
    __shared__ __align__(16) char smem[65536];
    const int tid = threadIdx.x, lane = tid & 63, w = tid >> 6;   // 8 waves
    const int wr = w >> 1, wc = w & 1;
    const int tj = blockIdx.x & 63, ti = blockIdx.x >> 6;         // ti 0..31
    const int kg = lane >> 4, r16 = lane & 15;

    f32x4 acc[4][4];
    #pragma unroll
    for (int mt = 0; mt < 4; mt++)
        #pragma unroll
        for (int nt = 0; nt < 4; nt++)
            acc[mt][nt] = (f32x4){0.f, 0.f, 0.f, 0.f};

    const uint4* gA = (const uint4*)(aT + (size_t)ti * 32768);    // 8i x 32h x 128n
    const uint4* gB = (const uint4*)(bT + (size_t)tj * 16384);    // 4j x 32h x 128n

    // ---- stage 1: two K=64 halves; A 32KB @0, B 16KB @32768 ----
    #pragma unroll
    for (int half = 0; half < 2; half++) {
        // async stage: LDS[row][c] = global chunk (c ^ (row&7))  (read undoes XOR)
        #pragma unroll
        for (int t = 0; t < 4; t++) {                    // A: 2048 chunks / 8w / 64l
            int q = w * 256 + t * 64 + lane;
            int row = q >> 3, c = q & 7;
            cp16_async(gA + row * 16 + half * 8 + (c ^ (row & 7)),
                       smem + ((w * 256 + t * 64) << 4));
        }
        #pragma unroll
        for (int t = 0; t < 2; t++) {                    // B: 1024 chunks
            int q = w * 128 + t * 64 + lane;
            int row = q >> 3, c = q & 7;
            cp16_async(gB + row * 16 + half * 8 + (c ^ (row & 7)),
                       smem + 32768 + ((w * 128 + t * 64) << 4));
        }
        __syncthreads();                                  // vmcnt(0) drained here

        #pragma unroll
        for (int ks2 = 0; ks2 < 2; ks2++) {
            int ch = ks2 * 4 + kg;
            bf8_t af[4];
            #pragma unroll
            for (int mt = 0; mt < 4; mt++) {
                int mm = wr * 64 + mt * 16 + r16;
                af[mt] = *(const bf8_t*)(smem + mm * 128 + ((ch ^ (mm & 7)) << 4));
            }
            #pragma unroll
            for (int nt = 0; nt < 4; nt++) {
                int nn = wc * 64 + nt * 16 + r16;
                bf8_t bfr = *(const bf8_t*)(smem + 32768 + nn * 128 +
                                            ((ch ^ (nn & 7)) << 4));
                #pragma unroll
                for (int mt = 0; mt < 4; mt++)
                    acc[mt][nt] = __builtin_amdgcn_mfma_f32_16x16x32_bf16(
                        af[mt], bfr, acc[mt][nt], 0, 0, 0);
            }
        }
        __syncthreads();   // LDS free for next half / the transpose
    }

    // ---- transpose accs -> O2b[p][k2] bf16 in LDS, A-fragment order ----
    // p = i_loc*4 + j_loc (32 pairs); k2 = (nn&31)*32 + (mm&31);
    // chunk c2=k2>>3; pc = c2 ^ ((c2>>3)&7) ^ (p&7) spreads banks.
    unsigned short* O2b = (unsigned short*)smem;        // 32 x 1024 bf16 = 64 KB
    #pragma unroll
    for (int mt = 0; mt < 4; mt++) {
        int mmb = wr * 64 + mt * 16 + kg * 4;           // + r (r stays in-chunk)
        #pragma unroll
        for (int nt = 0; nt < 4; nt++) {
            int nn = wc * 64 + nt * 16 + r16;
            int p  = ((mmb >> 5) << 2) | (nn >> 5);     // pair = i_loc*4 + j_loc
            int k2 = ((nn & 31) << 5) | (mmb & 31);
            int c2 = k2 >> 3;
            int pc = c2 ^ ((c2 >> 3) & 7) ^ (p & 7);
            *(uint2*)(O2b + p * 1024 + pc * 8 + (k2 & 7)) =
                make_uint2(pack2(acc[mt][nt][0], acc[mt][nt][1]),
                           pack2(acc[mt][nt][2], acc[mt][nt][3]));
        }
    }
    __syncthreads();

    // ---- stage 2: Z[32 pairs, 128] = O2[32,1024] @ Wo[1024,128] ----
    // Wave w -> z in [w*16, w*16+16): 32KB W2 slice read once, shared by the
    // 2 m-tiles. Depth-8 named ring (32 VGPR, live only in stage 2): ~7 W2
    // loads in flight -> per-iter L2 latency hidden; acc[4][4] is dead here
    // so peak pressure stays under the 3-waves/SIMD budget.
    f32x4 acc2[2];
    acc2[0] = (f32x4){0.f, 0.f, 0.f, 0.f};
    acc2[1] = (f32x4){0.f, 0.f, 0.f, 0.f};
    const unsigned short* O2r = O2b + r16 * 1024;        // A-row = pair (m-tile 0)
    const int psw = r16 & 7;                             // p&7 same for both m-tiles
    const unsigned short* wz = W2 + (size_t)w * 16384 + r16 * 32 + kg * 8;

#define W2LD(x) (*(const bf8_t*)(wz + (x) * 512))
    bf8_t w0 = W2LD(0), w1 = W2LD(1), w2 = W2LD(2), w3 = W2LD(3);
    bf8_t w4 = W2LD(4), w5 = W2LD(5), w6 = W2LD(6), w7 = W2LD(7);

// Snapshot wreg BEFORE the prefetch overwrites it (v4 bug: PF first -> MFMA
// consumed the future fragment). Compiler renames; load still issues early.
#define S2_ITER(s, wreg, PF)                                                  \
    {                                                                         \
        bf8_t wcur = wreg;                                                    \
        PF;                                                                   \
        int c2 = (s) * 4 + kg;                                                \
        int pc = c2 ^ ((c2 >> 3) & 7) ^ psw;                                  \
        bf8_t a0 = *(const bf8_t*)(O2r + pc * 8);                             \
        bf8_t a1 = *(const bf8_t*)(O2r + 16384 + pc * 8);                     \
        acc2[0] = __builtin_amdgcn_mfma_f32_16x16x32_bf16(a0, wcur, acc2[0],  \
                                                          0, 0, 0);           \
        acc2[1] = __builtin_amdgcn_mfma_f32_16x16x32_bf16(a1, wcur, acc2[1],  \
                                                          0, 0, 0);           \
    }

    #pragma unroll
    for (int sb = 0; sb < 4; sb++) {                     // sb compile-time
        S2_ITER(sb * 8 + 0, w0, if (sb < 3) w0 = W2LD(sb * 8 + 8))
        S2_ITER(sb * 8 + 1, w1, if (sb < 3) w1 = W2LD(sb * 8 + 9))
        S2_ITER(sb * 8 + 2, w2, if (sb < 3) w2 = W2LD(sb * 8 + 10))
        S2_ITER(sb * 8 + 3, w3, if (sb < 3) w3 = W2LD(sb * 8 + 11))
        S2_ITER(sb * 8 + 4, w4, if (sb < 3) w4 = W2LD(sb * 8 + 12))
        S2_ITER(sb * 8 + 5, w5, if (sb < 3) w5 = W2LD(sb * 8 + 13))
        S2_ITER(sb * 8 + 6, w6, if (sb < 3) w6 = W2LD(sb * 8 + 14))
        S2_ITER(sb * 8 + 7, w7, if (sb < 3) w7 = W2LD(sb * 8 + 15))
    }
#undef S2_ITER
#undef W2LD

    // ---- epilogue: scale by 1/(pair_mask+eps), add bias, store ----
    const int i0 = ti * 8, j0 = tj * 4;
    const int z = w * 16 + r16;
    const float boz = bo[z];
    #pragma unroll
    for (int mt = 0; mt < 2; mt++)
        #pragma unroll
        for (int r = 0; r < 4; r++) {
            int p = mt * 16 + kg * 4 + r;
            int i = i0 + (p >> 2), j = j0 + (p & 3);
            float recip = pmr[i * 256 + j];
            out[((size_t)(i * 256 + j)) * 128 + z] = acc2[mt][r] * recip + boz;
        }
}

// ---------------------------------------------------------------------------
extern "C" void kernel_launch(void* const* d_in, const int* in_sizes, int n_in,
                              void* d_out, int out_size, void* d_ws, size_t ws_size,
                              hipStream_t stream)
{
    const float* m    = (const float*)d_in[0];
    const float* mask = (const float*)d_in[1];
    const float* gam  = (const float*)d_in[2];
    const float* bet  = (const float*)d_in[3];
    const float* Wa   = (const float*)d_in[4];
    const float* ba   = (const float*)d_in[5];
    const float* Wb   = (const float*)d_in[6];
    const float* bb   = (const float*)d_in[7];
    const float* Wo   = (const float*)d_in[8];
    const float* bo   = (const float*)d_in[9];
    float* out = (float*)d_out;

    unsigned short* aT  = (unsigned short*)d_ws;           // 8192*128 bf16 = 2 MB
    unsigned short* bT  = aT + 8192 * 128;                 // 2 MB
    unsigned short* W2  = bT + 8192 * 128;                 // 128*1024 bf16 = 256 KB
    unsigned short* WTb = W2 + 128 * 1024;                 // 64*256 bf16 = 32 KB
    float* pmr = (float*)(WTb + 64 * 256);                 // 256*256 fp32 = 256 KB

    k_prep   <<<  64, 256, 0, stream>>>(Wa, Wb, WTb);
    k_ln_proj<<<2816, 256, 0, stream>>>(m, mask, gam, bet, WTb, ba, bb, Wo,
                                        aT, bT, W2, pmr);
    k_outer  <<<2048, 512, 0, stream>>>(aT, bT, W2, pmr, bo, out);
}